// Round 1
// baseline (1047.383 us; speedup 1.0000x reference)
//
#include <hip/hip_runtime.h>

#define N_TOTAL 1000000
#define N0 495616
#define N1 45056
#define N2 4096
#define E0 450560
#define E1 40960
#define D 128
#define P 4096

typedef _Float16 half8 __attribute__((ext_vector_type(8)));
typedef _Float16 half2v __attribute__((ext_vector_type(2)));
typedef float f32x4 __attribute__((ext_vector_type(4)));

// ---------------------------------------------------------------------------
// zero the accumulator region of the workspace (poisoned 0xAA before each call)
__global__ __launch_bounds__(256) void zero_kernel(float4* __restrict__ p, int n4) {
    int i = blockIdx.x * 256 + threadIdx.x;
    if (i < n4) p[i] = make_float4(0.f, 0.f, 0.f, 0.f);
}

// ---------------------------------------------------------------------------
// layer-0 aggregation: one wave per edge; lane handles 2 floats (512B row/edge)
__global__ __launch_bounds__(256) void agg0_kernel(
    const float* __restrict__ nf, const int* __restrict__ input_nodes,
    const int* __restrict__ esrc, const int* __restrict__ edst,
    float* __restrict__ neigh, float* __restrict__ deg) {
    int wave = (blockIdx.x * 256 + threadIdx.x) >> 6;
    int lane = threadIdx.x & 63;
    if (wave >= E0) return;
    int src = esrc[wave];
    int dst = edst[wave];
    int g   = input_nodes[src];
    const float2 v = *(const float2*)(nf + (long)g * D + lane * 2);
    float* o = neigh + (long)dst * D + lane * 2;
    atomicAdd(o, v.x);
    atomicAdd(o + 1, v.y);
    if (lane == 0) atomicAdd(deg + dst, 1.0f);
}

// ---------------------------------------------------------------------------
// layer-1 aggregation over f16 h1 rows (256B row/edge)
__global__ __launch_bounds__(256) void agg1_kernel(
    const _Float16* __restrict__ h1, const int* __restrict__ esrc,
    const int* __restrict__ edst, float* __restrict__ neigh, float* __restrict__ deg) {
    int wave = (blockIdx.x * 256 + threadIdx.x) >> 6;
    int lane = threadIdx.x & 63;
    if (wave >= E1) return;
    int src = esrc[wave];
    int dst = edst[wave];
    half2v v = *(const half2v*)(h1 + (long)src * D + lane * 2);
    float* o = neigh + (long)dst * D + lane * 2;
    atomicAdd(o, (float)v[0]);
    atomicAdd(o + 1, (float)v[1]);
    if (lane == 0) atomicAdd(deg + dst, 1.0f);
}

// ---------------------------------------------------------------------------
// mm0: h1 = relu([self | neigh_mean] @ [Wself; Wneigh] + b), output f16
// block = 256 threads = 4 waves; each wave computes 16 rows x 128 cols.
// W2T stored in LDS swizzled: element (n,k) at Wt[n][ (((k>>3)^n)&31)*8 + (k&7) ]
// -> b_frag reads are contiguous 16B with only 2-way bank aliasing (free).
__global__ __launch_bounds__(256) void mm0_kernel(
    const float* __restrict__ nf, const int* __restrict__ input_nodes,
    const float* __restrict__ neigh, const float* __restrict__ deg,
    const float* __restrict__ Wself, const float* __restrict__ Wneigh,
    const float* __restrict__ bias, _Float16* __restrict__ h1) {
    __shared__ _Float16 Wt[128][256];   // 64 KB exactly
    const int tid = threadIdx.x;
    for (int i = tid; i < 128 * 256; i += 256) {
        int k = i >> 7, n = i & 127;
        float w = (k < 128) ? Wself[k * 128 + n] : Wneigh[(k - 128) * 128 + n];
        Wt[n][((((k >> 3) ^ n) & 31) << 3) | (k & 7)] = (_Float16)w;
    }
    __syncthreads();

    const int waveId = tid >> 6, lane = tid & 63;
    const int quad = lane >> 4;
    const int m = lane & 15;
    const int row = blockIdx.x * 64 + waveId * 16 + m;
    const int g = input_nodes[row];
    const float* __restrict__ srow = nf + (long)g * D;
    const float* __restrict__ nrow = neigh + (long)row * D;
    const float invdeg = 1.0f / fmaxf(deg[row], 1.0f);

    f32x4 acc[8];
#pragma unroll
    for (int c = 0; c < 8; c++) { acc[c][0] = 0.f; acc[c][1] = 0.f; acc[c][2] = 0.f; acc[c][3] = 0.f; }

#pragma unroll
    for (int s = 0; s < 8; s++) {
        half8 a;
        if (s < 4) {
            const int k0 = s * 32 + quad * 8;
            float4 u = *(const float4*)(srow + k0);
            float4 v = *(const float4*)(srow + k0 + 4);
            a[0] = (_Float16)u.x; a[1] = (_Float16)u.y; a[2] = (_Float16)u.z; a[3] = (_Float16)u.w;
            a[4] = (_Float16)v.x; a[5] = (_Float16)v.y; a[6] = (_Float16)v.z; a[7] = (_Float16)v.w;
        } else {
            const int k0 = (s - 4) * 32 + quad * 8;
            float4 u = *(const float4*)(nrow + k0);
            float4 v = *(const float4*)(nrow + k0 + 4);
            a[0] = (_Float16)(u.x * invdeg); a[1] = (_Float16)(u.y * invdeg);
            a[2] = (_Float16)(u.z * invdeg); a[3] = (_Float16)(u.w * invdeg);
            a[4] = (_Float16)(v.x * invdeg); a[5] = (_Float16)(v.y * invdeg);
            a[6] = (_Float16)(v.z * invdeg); a[7] = (_Float16)(v.w * invdeg);
        }
        const int kb = s * 4 + quad;   // 16B-block index of this quad's k-slice
#pragma unroll
        for (int c = 0; c < 8; c++) {
            const int n = c * 16 + m;
            half8 b = *(const half8*)&Wt[n][((kb ^ (n & 31)) & 31) << 3];
            acc[c] = __builtin_amdgcn_mfma_f32_16x16x32_f16(a, b, acc[c], 0, 0, 0);
        }
    }

    const int orow = blockIdx.x * 64 + waveId * 16 + quad * 4;
#pragma unroll
    for (int c = 0; c < 8; c++) {
        const int col = c * 16 + m;
        const float bb = bias[col];
#pragma unroll
        for (int r = 0; r < 4; r++) {
            float vv = acc[c][r] + bb;
            vv = fmaxf(vv, 0.0f);
            h1[(long)(orow + r) * D + col] = (_Float16)vv;
        }
    }
}

// ---------------------------------------------------------------------------
// mm1: h2 = [h1_self | neigh_mean] @ [Wself1; Wneigh1] + b1, output fp32, no relu
__global__ __launch_bounds__(256) void mm1_kernel(
    const _Float16* __restrict__ h1,
    const float* __restrict__ neigh, const float* __restrict__ deg,
    const float* __restrict__ Wself, const float* __restrict__ Wneigh,
    const float* __restrict__ bias, float* __restrict__ h2) {
    __shared__ _Float16 Wt[128][256];
    const int tid = threadIdx.x;
    for (int i = tid; i < 128 * 256; i += 256) {
        int k = i >> 7, n = i & 127;
        float w = (k < 128) ? Wself[k * 128 + n] : Wneigh[(k - 128) * 128 + n];
        Wt[n][((((k >> 3) ^ n) & 31) << 3) | (k & 7)] = (_Float16)w;
    }
    __syncthreads();

    const int waveId = tid >> 6, lane = tid & 63;
    const int quad = lane >> 4;
    const int m = lane & 15;
    const int row = blockIdx.x * 64 + waveId * 16 + m;
    const _Float16* __restrict__ srow = h1 + (long)row * D;
    const float* __restrict__ nrow = neigh + (long)row * D;
    const float invdeg = 1.0f / fmaxf(deg[row], 1.0f);

    f32x4 acc[8];
#pragma unroll
    for (int c = 0; c < 8; c++) { acc[c][0] = 0.f; acc[c][1] = 0.f; acc[c][2] = 0.f; acc[c][3] = 0.f; }

#pragma unroll
    for (int s = 0; s < 8; s++) {
        half8 a;
        if (s < 4) {
            const int k0 = s * 32 + quad * 8;
            a = *(const half8*)(srow + k0);
        } else {
            const int k0 = (s - 4) * 32 + quad * 8;
            float4 u = *(const float4*)(nrow + k0);
            float4 v = *(const float4*)(nrow + k0 + 4);
            a[0] = (_Float16)(u.x * invdeg); a[1] = (_Float16)(u.y * invdeg);
            a[2] = (_Float16)(u.z * invdeg); a[3] = (_Float16)(u.w * invdeg);
            a[4] = (_Float16)(v.x * invdeg); a[5] = (_Float16)(v.y * invdeg);
            a[6] = (_Float16)(v.z * invdeg); a[7] = (_Float16)(v.w * invdeg);
        }
        const int kb = s * 4 + quad;
#pragma unroll
        for (int c = 0; c < 8; c++) {
            const int n = c * 16 + m;
            half8 b = *(const half8*)&Wt[n][((kb ^ (n & 31)) & 31) << 3];
            acc[c] = __builtin_amdgcn_mfma_f32_16x16x32_f16(a, b, acc[c], 0, 0, 0);
        }
    }

    const int orow = blockIdx.x * 64 + waveId * 16 + quad * 4;
#pragma unroll
    for (int c = 0; c < 8; c++) {
        const int col = c * 16 + m;
        const float bb = bias[col];
#pragma unroll
        for (int r = 0; r < 4; r++) {
            h2[(long)(orow + r) * D + col] = acc[c][r] + bb;
        }
    }
}

// ---------------------------------------------------------------------------
// final gather: out rows 0..16383 = h2[pos_src|pos_dst|neg_src|neg_dst]
__global__ __launch_bounds__(256) void gather_out_kernel(
    const float* __restrict__ h2,
    const int* __restrict__ i0, const int* __restrict__ i1,
    const int* __restrict__ i2, const int* __restrict__ i3,
    float* __restrict__ out) {
    int wave = (blockIdx.x * 256 + threadIdx.x) >> 6;
    int lane = threadIdx.x & 63;
    int sel = wave >> 12;
    int i = wave & (P - 1);
    const int* arr = (sel == 0) ? i0 : (sel == 1) ? i1 : (sel == 2) ? i2 : i3;
    int idx = arr[i];
    float2 v = *(const float2*)(h2 + (long)idx * D + lane * 2);
    *(float2*)(out + (long)wave * D + lane * 2) = v;
}

// ---------------------------------------------------------------------------
extern "C" void kernel_launch(void* const* d_in, const int* in_sizes, int n_in,
                              void* d_out, int out_size, void* d_ws, size_t ws_size,
                              hipStream_t stream) {
    const float* nf          = (const float*)d_in[0];
    const int* input_nodes   = (const int*)d_in[1];
    const int* esrc0         = (const int*)d_in[2];
    const int* edst0         = (const int*)d_in[3];
    const int* esrc1         = (const int*)d_in[4];
    const int* edst1         = (const int*)d_in[5];
    const int* pos_src       = (const int*)d_in[6];
    const int* pos_dst       = (const int*)d_in[7];
    const int* neg_src       = (const int*)d_in[8];
    const int* neg_dst       = (const int*)d_in[9];
    const float* Wself0      = (const float*)d_in[10];
    const float* Wneigh0     = (const float*)d_in[11];
    const float* b0          = (const float*)d_in[12];
    const float* Wself1      = (const float*)d_in[13];
    const float* Wneigh1     = (const float*)d_in[14];
    const float* b1          = (const float*)d_in[15];

    char* ws = (char*)d_ws;
    float* neigh0 = (float*)ws; ws += (size_t)N1 * D * 4;
    float* deg0   = (float*)ws; ws += (size_t)N1 * 4;
    float* neigh1 = (float*)ws; ws += (size_t)N2 * D * 4;
    float* deg1   = (float*)ws; ws += (size_t)N2 * 4;
    size_t zero_bytes = (size_t)(ws - (char*)d_ws);   // 25,362,432 B
    _Float16* h1  = (_Float16*)ws; ws += (size_t)N1 * D * 2;
    float* h2     = (float*)ws; ws += (size_t)N2 * D * 4;

    int n4 = (int)(zero_bytes / 16);                  // 1,585,152 -> 6192 blocks
    zero_kernel<<<(n4 + 255) / 256, 256, 0, stream>>>((float4*)d_ws, n4);

    agg0_kernel<<<E0 / 4, 256, 0, stream>>>(nf, input_nodes, esrc0, edst0, neigh0, deg0);
    mm0_kernel<<<N1 / 64, 256, 0, stream>>>(nf, input_nodes, neigh0, deg0,
                                            Wself0, Wneigh0, b0, h1);
    agg1_kernel<<<E1 / 4, 256, 0, stream>>>(h1, esrc1, edst1, neigh1, deg1);
    mm1_kernel<<<N2 / 64, 256, 0, stream>>>(h1, neigh1, deg1, Wself1, Wneigh1, b1, h2);
    gather_out_kernel<<<(4 * P) / 4, 256, 0, stream>>>(h2, pos_src, pos_dst,
                                                       neg_src, neg_dst, (float*)d_out);
}

// Round 2
// 752.069 us; speedup vs baseline: 1.3927x; 1.3927x over previous
//
#include <hip/hip_runtime.h>

#define N_TOTAL 1000000
#define N0 495616
#define N1 45056
#define N2 4096
#define E0 450560
#define E1 40960
#define D 128
#define P 4096
#define NCNT (N1 + N2)        // 49152 combined histogram size
#define NB   48               // scan blocks: 48 * 1024 = 49152

typedef _Float16 half8 __attribute__((ext_vector_type(8)));
typedef _Float16 half2v __attribute__((ext_vector_type(2)));
typedef float f32x4 __attribute__((ext_vector_type(4)));

// ---------------------------------------------------------------------------
// zero the combined degree-histogram (ws is poisoned 0xAA before each call)
__global__ __launch_bounds__(256) void zero_kernel(int* __restrict__ p, int n) {
    int i = blockIdx.x * 256 + threadIdx.x;
    if (i < n) p[i] = 0;
}

// ---------------------------------------------------------------------------
// combined degree histogram for both layers (int atomics on 49K counters, L2-hot)
__global__ __launch_bounds__(256) void hist_kernel(
    const int* __restrict__ edst0, const int* __restrict__ edst1,
    int* __restrict__ cnt) {
    int e = blockIdx.x * 256 + threadIdx.x;
    if (e < E0) {
        atomicAdd(&cnt[edst0[e]], 1);
    } else if (e < E0 + E1) {
        atomicAdd(&cnt[N1 + edst1[e - E0]], 1);
    }
}

// ---------------------------------------------------------------------------
// exclusive scan, 3-pass. Pass A: per-1024-block scan (wave shuffles + LDS)
__global__ __launch_bounds__(1024) void scanA_kernel(
    const int* __restrict__ cnt, int* __restrict__ off, int* __restrict__ bsum) {
    __shared__ int sbuf[16];
    int tid = threadIdx.x, lane = tid & 63, w = tid >> 6;
    int i = blockIdx.x * 1024 + tid;
    int v = (i < NCNT) ? cnt[i] : 0;
    int x = v;
#pragma unroll
    for (int o = 1; o < 64; o <<= 1) { int t = __shfl_up(x, o, 64); if (lane >= o) x += t; }
    if (lane == 63) sbuf[w] = x;
    __syncthreads();
    if (w == 0) {
        int s = (lane < 16) ? sbuf[lane] : 0;
#pragma unroll
        for (int o = 1; o < 16; o <<= 1) { int t = __shfl_up(s, o, 64); if (lane >= o) s += t; }
        if (lane < 16) sbuf[lane] = s;   // inclusive wave sums
    }
    __syncthreads();
    int wbase = (w > 0) ? sbuf[w - 1] : 0;
    if (i < NCNT) off[i] = wbase + x - v;          // block-local exclusive
    if (tid == 1023) bsum[blockIdx.x] = wbase + x; // block total
}

// Pass B: exclusive scan of the 48 block sums (one wave)
__global__ __launch_bounds__(64) void scanB_kernel(int* __restrict__ bsum) {
    int lane = threadIdx.x;
    int v = (lane < NB) ? bsum[lane] : 0;
    int x = v;
#pragma unroll
    for (int o = 1; o < 64; o <<= 1) { int t = __shfl_up(x, o, 64); if (lane >= o) x += t; }
    if (lane < NB) bsum[lane] = x - v;
}

// Pass C: add block offsets
__global__ __launch_bounds__(1024) void scanC_kernel(int* __restrict__ off,
                                                     const int* __restrict__ bsum) {
    int i = blockIdx.x * 1024 + threadIdx.x;
    if (i < NCNT) off[i] += bsum[blockIdx.x];
}

// ---------------------------------------------------------------------------
// scatter edges into dst-grouped order. Folds input_nodes[] indirection for
// layer 0. After this kernel, off[d] == end-of-bucket d (agg uses off[d]-cnt[d]).
__global__ __launch_bounds__(256) void scatter_kernel(
    const int* __restrict__ esrc0, const int* __restrict__ edst0,
    const int* __restrict__ esrc1, const int* __restrict__ edst1,
    const int* __restrict__ input_nodes,
    int* __restrict__ off, int* __restrict__ eg) {
    int e = blockIdx.x * 256 + threadIdx.x;
    if (e < E0) {
        int d = edst0[e];
        int p = atomicAdd(&off[d], 1);
        eg[p] = input_nodes[esrc0[e]];     // global node id
    } else if (e < E0 + E1) {
        int ee = e - E0;
        int d = N1 + edst1[ee];
        int p = atomicAdd(&off[d], 1);
        eg[p] = esrc1[ee];                 // h1 row index
    }
}

// ---------------------------------------------------------------------------
// layer-0 mean aggregation: one wave per dst row, registers only, single write.
// Lane l holds edge-id l; __shfl broadcast makes row loads independent (MLP).
__global__ __launch_bounds__(256) void agg0_kernel(
    const float* __restrict__ nf, const int* __restrict__ cnt,
    const int* __restrict__ off, const int* __restrict__ eg,
    _Float16* __restrict__ hn0) {
    int wv = (blockIdx.x * 256 + threadIdx.x) >> 6;
    int lane = threadIdx.x & 63;
    if (wv >= N1) return;
    int c = cnt[wv];
    int end = off[wv];
    int beg = end - c;
    int myeg = (lane < c) ? eg[beg + lane] : 0;
    float ax = 0.f, ay = 0.f;
    int cc = (c < 64) ? c : 64;
    for (int j = 0; j < cc; j++) {
        int g = __shfl(myeg, j, 64);
        float2 v = *(const float2*)(nf + (long)g * D + lane * 2);
        ax += v.x; ay += v.y;
    }
    for (int j = 64; j < c; j++) {           // vanishingly rare (avg deg ~10)
        int g = eg[beg + j];
        float2 v = *(const float2*)(nf + (long)g * D + lane * 2);
        ax += v.x; ay += v.y;
    }
    float inv = 1.0f / fmaxf((float)c, 1.0f);
    half2v o; o[0] = (_Float16)(ax * inv); o[1] = (_Float16)(ay * inv);
    *(half2v*)(hn0 + (long)wv * D + lane * 2) = o;
}

// ---------------------------------------------------------------------------
// layer-1 mean aggregation over f16 h1 rows (h1 is 11.5 MB, cache-resident)
__global__ __launch_bounds__(256) void agg1_kernel(
    const _Float16* __restrict__ h1, const int* __restrict__ cnt,
    const int* __restrict__ off, const int* __restrict__ eg,
    _Float16* __restrict__ hn1) {
    int wv = (blockIdx.x * 256 + threadIdx.x) >> 6;
    int lane = threadIdx.x & 63;
    if (wv >= N2) return;
    int c = cnt[N1 + wv];
    int end = off[N1 + wv];
    int beg = end - c;
    int myeg = (lane < c) ? eg[beg + lane] : 0;
    float ax = 0.f, ay = 0.f;
    int cc = (c < 64) ? c : 64;
    for (int j = 0; j < cc; j++) {
        int r = __shfl(myeg, j, 64);
        half2v v = *(const half2v*)(h1 + (long)r * D + lane * 2);
        ax += (float)v[0]; ay += (float)v[1];
    }
    for (int j = 64; j < c; j++) {
        int r = eg[beg + j];
        half2v v = *(const half2v*)(h1 + (long)r * D + lane * 2);
        ax += (float)v[0]; ay += (float)v[1];
    }
    float inv = 1.0f / fmaxf((float)c, 1.0f);
    half2v o; o[0] = (_Float16)(ax * inv); o[1] = (_Float16)(ay * inv);
    *(half2v*)(hn1 + (long)wv * D + lane * 2) = o;
}

// ---------------------------------------------------------------------------
// mm0: h1 = relu([self | neigh_mean] @ [Wself; Wneigh] + b), f16 out.
// block = 4 waves; wave computes 16 rows x 128 cols via mfma_f32_16x16x32_f16.
// W2T in LDS swizzled so b-frag reads are 16B contiguous, 2-way aliasing (free).
__global__ __launch_bounds__(256) void mm0_kernel(
    const float* __restrict__ nf, const int* __restrict__ input_nodes,
    const _Float16* __restrict__ hn0,
    const float* __restrict__ Wself, const float* __restrict__ Wneigh,
    const float* __restrict__ bias, _Float16* __restrict__ h1) {
    __shared__ _Float16 Wt[128][256];   // 64 KB
    const int tid = threadIdx.x;
    for (int i = tid; i < 128 * 256; i += 256) {
        int k = i >> 7, n = i & 127;
        float w = (k < 128) ? Wself[k * 128 + n] : Wneigh[(k - 128) * 128 + n];
        Wt[n][((((k >> 3) ^ n) & 31) << 3) | (k & 7)] = (_Float16)w;
    }
    __syncthreads();

    const int waveId = tid >> 6, lane = tid & 63;
    const int quad = lane >> 4;
    const int m = lane & 15;
    const int row = blockIdx.x * 64 + waveId * 16 + m;
    const int g = input_nodes[row];
    const float* __restrict__ srow = nf + (long)g * D;
    const _Float16* __restrict__ nrow = hn0 + (long)row * D;

    f32x4 acc[8];
#pragma unroll
    for (int c = 0; c < 8; c++) { acc[c][0] = 0.f; acc[c][1] = 0.f; acc[c][2] = 0.f; acc[c][3] = 0.f; }

#pragma unroll
    for (int s = 0; s < 8; s++) {
        half8 a;
        if (s < 4) {
            const int k0 = s * 32 + quad * 8;
            float4 u = *(const float4*)(srow + k0);
            float4 v = *(const float4*)(srow + k0 + 4);
            a[0] = (_Float16)u.x; a[1] = (_Float16)u.y; a[2] = (_Float16)u.z; a[3] = (_Float16)u.w;
            a[4] = (_Float16)v.x; a[5] = (_Float16)v.y; a[6] = (_Float16)v.z; a[7] = (_Float16)v.w;
        } else {
            const int k0 = (s - 4) * 32 + quad * 8;
            a = *(const half8*)(nrow + k0);
        }
        const int kb = s * 4 + quad;
#pragma unroll
        for (int c = 0; c < 8; c++) {
            const int n = c * 16 + m;
            half8 b = *(const half8*)&Wt[n][((kb ^ (n & 31)) & 31) << 3];
            acc[c] = __builtin_amdgcn_mfma_f32_16x16x32_f16(a, b, acc[c], 0, 0, 0);
        }
    }

    const int orow = blockIdx.x * 64 + waveId * 16 + quad * 4;
#pragma unroll
    for (int c = 0; c < 8; c++) {
        const int col = c * 16 + m;
        const float bb = bias[col];
#pragma unroll
        for (int r = 0; r < 4; r++) {
            float vv = acc[c][r] + bb;
            vv = fmaxf(vv, 0.0f);
            h1[(long)(orow + r) * D + col] = (_Float16)vv;
        }
    }
}

// ---------------------------------------------------------------------------
// mm1: h2 = [h1_self | neigh_mean] @ [Wself1; Wneigh1] + b1, fp32 out, no relu
__global__ __launch_bounds__(256) void mm1_kernel(
    const _Float16* __restrict__ h1, const _Float16* __restrict__ hn1,
    const float* __restrict__ Wself, const float* __restrict__ Wneigh,
    const float* __restrict__ bias, float* __restrict__ h2) {
    __shared__ _Float16 Wt[128][256];
    const int tid = threadIdx.x;
    for (int i = tid; i < 128 * 256; i += 256) {
        int k = i >> 7, n = i & 127;
        float w = (k < 128) ? Wself[k * 128 + n] : Wneigh[(k - 128) * 128 + n];
        Wt[n][((((k >> 3) ^ n) & 31) << 3) | (k & 7)] = (_Float16)w;
    }
    __syncthreads();

    const int waveId = tid >> 6, lane = tid & 63;
    const int quad = lane >> 4;
    const int m = lane & 15;
    const int row = blockIdx.x * 64 + waveId * 16 + m;
    const _Float16* __restrict__ srow = h1 + (long)row * D;
    const _Float16* __restrict__ nrow = hn1 + (long)row * D;

    f32x4 acc[8];
#pragma unroll
    for (int c = 0; c < 8; c++) { acc[c][0] = 0.f; acc[c][1] = 0.f; acc[c][2] = 0.f; acc[c][3] = 0.f; }

#pragma unroll
    for (int s = 0; s < 8; s++) {
        half8 a;
        if (s < 4) {
            a = *(const half8*)(srow + s * 32 + quad * 8);
        } else {
            a = *(const half8*)(nrow + (s - 4) * 32 + quad * 8);
        }
        const int kb = s * 4 + quad;
#pragma unroll
        for (int c = 0; c < 8; c++) {
            const int n = c * 16 + m;
            half8 b = *(const half8*)&Wt[n][((kb ^ (n & 31)) & 31) << 3];
            acc[c] = __builtin_amdgcn_mfma_f32_16x16x32_f16(a, b, acc[c], 0, 0, 0);
        }
    }

    const int orow = blockIdx.x * 64 + waveId * 16 + quad * 4;
#pragma unroll
    for (int c = 0; c < 8; c++) {
        const int col = c * 16 + m;
        const float bb = bias[col];
#pragma unroll
        for (int r = 0; r < 4; r++) {
            h2[(long)(orow + r) * D + col] = acc[c][r] + bb;
        }
    }
}

// ---------------------------------------------------------------------------
// final gather: out rows 0..16383 = h2[pos_src|pos_dst|neg_src|neg_dst]
__global__ __launch_bounds__(256) void gather_out_kernel(
    const float* __restrict__ h2,
    const int* __restrict__ i0, const int* __restrict__ i1,
    const int* __restrict__ i2, const int* __restrict__ i3,
    float* __restrict__ out) {
    int wave = (blockIdx.x * 256 + threadIdx.x) >> 6;
    int lane = threadIdx.x & 63;
    int sel = wave >> 12;
    int i = wave & (P - 1);
    const int* arr = (sel == 0) ? i0 : (sel == 1) ? i1 : (sel == 2) ? i2 : i3;
    int idx = arr[i];
    float2 v = *(const float2*)(h2 + (long)idx * D + lane * 2);
    *(float2*)(out + (long)wave * D + lane * 2) = v;
}

// ---------------------------------------------------------------------------
extern "C" void kernel_launch(void* const* d_in, const int* in_sizes, int n_in,
                              void* d_out, int out_size, void* d_ws, size_t ws_size,
                              hipStream_t stream) {
    const float* nf          = (const float*)d_in[0];
    const int* input_nodes   = (const int*)d_in[1];
    const int* esrc0         = (const int*)d_in[2];
    const int* edst0         = (const int*)d_in[3];
    const int* esrc1         = (const int*)d_in[4];
    const int* edst1         = (const int*)d_in[5];
    const int* pos_src       = (const int*)d_in[6];
    const int* pos_dst       = (const int*)d_in[7];
    const int* neg_src       = (const int*)d_in[8];
    const int* neg_dst       = (const int*)d_in[9];
    const float* Wself0      = (const float*)d_in[10];
    const float* Wneigh0     = (const float*)d_in[11];
    const float* b0          = (const float*)d_in[12];
    const float* Wself1      = (const float*)d_in[13];
    const float* Wneigh1     = (const float*)d_in[14];
    const float* b1          = (const float*)d_in[15];

    char* ws = (char*)d_ws;
    int* cnt  = (int*)ws; ws += (size_t)NCNT * 4;
    int* off  = (int*)ws; ws += (size_t)NCNT * 4;
    int* bsum = (int*)ws; ws += 64 * 4;
    int* eg   = (int*)ws; ws += (size_t)(E0 + E1) * 4;
    _Float16* hn0 = (_Float16*)ws; ws += (size_t)N1 * D * 2;
    _Float16* h1  = (_Float16*)ws; ws += (size_t)N1 * D * 2;
    _Float16* hn1 = (_Float16*)ws; ws += (size_t)N2 * D * 2;
    float* h2     = (float*)ws; ws += (size_t)N2 * D * 4;

    const int EALL = E0 + E1;

    zero_kernel<<<(NCNT + 255) / 256, 256, 0, stream>>>(cnt, NCNT);
    hist_kernel<<<(EALL + 255) / 256, 256, 0, stream>>>(edst0, edst1, cnt);
    scanA_kernel<<<NB, 1024, 0, stream>>>(cnt, off, bsum);
    scanB_kernel<<<1, 64, 0, stream>>>(bsum);
    scanC_kernel<<<NB, 1024, 0, stream>>>(off, bsum);
    scatter_kernel<<<(EALL + 255) / 256, 256, 0, stream>>>(
        esrc0, edst0, esrc1, edst1, input_nodes, off, eg);

    agg0_kernel<<<(N1 * 64 + 255) / 256, 256, 0, stream>>>(nf, cnt, off, eg, hn0);
    mm0_kernel<<<N1 / 64, 256, 0, stream>>>(nf, input_nodes, hn0, Wself0, Wneigh0, b0, h1);
    agg1_kernel<<<(N2 * 64 + 255) / 256, 256, 0, stream>>>(h1, cnt, off, eg, hn1);
    mm1_kernel<<<N2 / 64, 256, 0, stream>>>(h1, hn1, Wself1, Wneigh1, b1, h2);
    gather_out_kernel<<<(4 * P) / 4, 256, 0, stream>>>(h2, pos_src, pos_dst,
                                                       neg_src, neg_dst, (float*)d_out);
}

// Round 3
// 733.192 us; speedup vs baseline: 1.4285x; 1.0257x over previous
//
#include <hip/hip_runtime.h>

#define N_TOTAL 1000000
#define N0 495616
#define N1 45056
#define N2 4096
#define E0 450560
#define E1 40960
#define D 128
#define P 4096
#define NCNT (N1 + N2)        // 49152 combined histogram size
#define NB   48               // scan blocks: 48 * 1024 = 49152

typedef _Float16 half8 __attribute__((ext_vector_type(8)));
typedef _Float16 half4 __attribute__((ext_vector_type(4)));
typedef _Float16 half2v __attribute__((ext_vector_type(2)));
typedef float f32x4 __attribute__((ext_vector_type(4)));

// ---------------------------------------------------------------------------
// zero the combined degree-histogram (ws is poisoned 0xAA before each call)
__global__ __launch_bounds__(256) void zero_kernel(int* __restrict__ p, int n) {
    int i = blockIdx.x * 256 + threadIdx.x;
    if (i < n) p[i] = 0;
}

// ---------------------------------------------------------------------------
// combined degree histogram for both layers (int atomics on 49K counters, L2-hot)
__global__ __launch_bounds__(256) void hist_kernel(
    const int* __restrict__ edst0, const int* __restrict__ edst1,
    int* __restrict__ cnt) {
    int e = blockIdx.x * 256 + threadIdx.x;
    if (e < E0) {
        atomicAdd(&cnt[edst0[e]], 1);
    } else if (e < E0 + E1) {
        atomicAdd(&cnt[N1 + edst1[e - E0]], 1);
    }
}

// ---------------------------------------------------------------------------
// exclusive scan, 3-pass. Pass A: per-1024-block scan (wave shuffles + LDS)
__global__ __launch_bounds__(1024) void scanA_kernel(
    const int* __restrict__ cnt, int* __restrict__ off, int* __restrict__ bsum) {
    __shared__ int sbuf[16];
    int tid = threadIdx.x, lane = tid & 63, w = tid >> 6;
    int i = blockIdx.x * 1024 + tid;
    int v = (i < NCNT) ? cnt[i] : 0;
    int x = v;
#pragma unroll
    for (int o = 1; o < 64; o <<= 1) { int t = __shfl_up(x, o, 64); if (lane >= o) x += t; }
    if (lane == 63) sbuf[w] = x;
    __syncthreads();
    if (w == 0) {
        int s = (lane < 16) ? sbuf[lane] : 0;
#pragma unroll
        for (int o = 1; o < 16; o <<= 1) { int t = __shfl_up(s, o, 64); if (lane >= o) s += t; }
        if (lane < 16) sbuf[lane] = s;   // inclusive wave sums
    }
    __syncthreads();
    int wbase = (w > 0) ? sbuf[w - 1] : 0;
    if (i < NCNT) off[i] = wbase + x - v;          // block-local exclusive
    if (tid == 1023) bsum[blockIdx.x] = wbase + x; // block total
}

// Pass B: exclusive scan of the 48 block sums (one wave)
__global__ __launch_bounds__(64) void scanB_kernel(int* __restrict__ bsum) {
    int lane = threadIdx.x;
    int v = (lane < NB) ? bsum[lane] : 0;
    int x = v;
#pragma unroll
    for (int o = 1; o < 64; o <<= 1) { int t = __shfl_up(x, o, 64); if (lane >= o) x += t; }
    if (lane < NB) bsum[lane] = x - v;
}

// Pass C: add block offsets
__global__ __launch_bounds__(1024) void scanC_kernel(int* __restrict__ off,
                                                     const int* __restrict__ bsum) {
    int i = blockIdx.x * 1024 + threadIdx.x;
    if (i < NCNT) off[i] += bsum[blockIdx.x];
}

// ---------------------------------------------------------------------------
// scatter edges into dst-grouped order. Folds input_nodes[] indirection for
// layer 0. After this kernel, off[d] == end-of-bucket d (agg uses off[d]-cnt[d]).
__global__ __launch_bounds__(256) void scatter_kernel(
    const int* __restrict__ esrc0, const int* __restrict__ edst0,
    const int* __restrict__ esrc1, const int* __restrict__ edst1,
    const int* __restrict__ input_nodes,
    int* __restrict__ off, int* __restrict__ eg) {
    int e = blockIdx.x * 256 + threadIdx.x;
    if (e < E0) {
        int d = edst0[e];
        int p = atomicAdd(&off[d], 1);
        eg[p] = input_nodes[esrc0[e]];     // global node id
    } else if (e < E0 + E1) {
        int ee = e - E0;
        int d = N1 + edst1[ee];
        int p = atomicAdd(&off[d], 1);
        eg[p] = esrc1[ee];                 // h1 row index
    }
}

// ---------------------------------------------------------------------------
// layer-0 mean aggregation: one wave per dst row. Two 32-lane halves process
// alternating edges with float4 (16B) loads; combine via shfl_xor(32).
// Lane l pre-holds edge-id l; __shfl broadcast keeps row loads independent.
__global__ __launch_bounds__(256) void agg0_kernel(
    const float* __restrict__ nf, const int* __restrict__ cnt,
    const int* __restrict__ off, const int* __restrict__ eg,
    _Float16* __restrict__ hn0) {
    int wv = (blockIdx.x * 256 + threadIdx.x) >> 6;
    int lane = threadIdx.x & 63;
    if (wv >= N1) return;
    int c = cnt[wv];
    int beg = off[wv] - c;
    int myeg = (lane < c) ? eg[beg + lane] : 0;
    int h = lane >> 5;             // half id: 0 -> even edges, 1 -> odd edges
    int col = (lane & 31) * 4;     // float column
    float ax = 0.f, ay = 0.f, az = 0.f, aw = 0.f;
    int cc = (c < 64) ? c : 64;
#pragma unroll 2
    for (int j = h; j < cc; j += 2) {
        int g = __shfl(myeg, j, 64);
        float4 v = *(const float4*)(nf + (long)g * D + col);
        ax += v.x; ay += v.y; az += v.z; aw += v.w;
    }
    for (int j = 64 + h; j < c; j += 2) {   // vanishingly rare (avg deg ~10)
        int g = eg[beg + j];
        float4 v = *(const float4*)(nf + (long)g * D + col);
        ax += v.x; ay += v.y; az += v.z; aw += v.w;
    }
    ax += __shfl_xor(ax, 32, 64);
    ay += __shfl_xor(ay, 32, 64);
    az += __shfl_xor(az, 32, 64);
    aw += __shfl_xor(aw, 32, 64);
    if (lane < 32) {
        float inv = 1.0f / fmaxf((float)c, 1.0f);
        half4 o;
        o[0] = (_Float16)(ax * inv); o[1] = (_Float16)(ay * inv);
        o[2] = (_Float16)(az * inv); o[3] = (_Float16)(aw * inv);
        *(half4*)(hn0 + (long)wv * D + col) = o;
    }
}

// ---------------------------------------------------------------------------
// layer-1 mean aggregation over f16 h1 rows (h1 is 11.5 MB, cache-resident).
// Same half-split structure, half4 (8B) loads.
__global__ __launch_bounds__(256) void agg1_kernel(
    const _Float16* __restrict__ h1, const int* __restrict__ cnt,
    const int* __restrict__ off, const int* __restrict__ eg,
    _Float16* __restrict__ hn1) {
    int wv = (blockIdx.x * 256 + threadIdx.x) >> 6;
    int lane = threadIdx.x & 63;
    if (wv >= N2) return;
    int c = cnt[N1 + wv];
    int beg = off[N1 + wv] - c;
    int myeg = (lane < c) ? eg[beg + lane] : 0;
    int h = lane >> 5;
    int col = (lane & 31) * 4;     // f16 column
    float ax = 0.f, ay = 0.f, az = 0.f, aw = 0.f;
    int cc = (c < 64) ? c : 64;
#pragma unroll 2
    for (int j = h; j < cc; j += 2) {
        int r = __shfl(myeg, j, 64);
        half4 v = *(const half4*)(h1 + (long)r * D + col);
        ax += (float)v[0]; ay += (float)v[1]; az += (float)v[2]; aw += (float)v[3];
    }
    for (int j = 64 + h; j < c; j += 2) {
        int r = eg[beg + j];
        half4 v = *(const half4*)(h1 + (long)r * D + col);
        ax += (float)v[0]; ay += (float)v[1]; az += (float)v[2]; aw += (float)v[3];
    }
    ax += __shfl_xor(ax, 32, 64);
    ay += __shfl_xor(ay, 32, 64);
    az += __shfl_xor(az, 32, 64);
    aw += __shfl_xor(aw, 32, 64);
    if (lane < 32) {
        float inv = 1.0f / fmaxf((float)c, 1.0f);
        half4 o;
        o[0] = (_Float16)(ax * inv); o[1] = (_Float16)(ay * inv);
        o[2] = (_Float16)(az * inv); o[3] = (_Float16)(aw * inv);
        *(half4*)(hn1 + (long)wv * D + col) = o;
    }
}

// ---------------------------------------------------------------------------
// mm0: h1 = relu([self | neigh_mean] @ [Wself; Wneigh] + b), f16 out.
// block = 4 waves; wave computes 16 rows x 128 cols via mfma_f32_16x16x32_f16.
// W2T in LDS swizzled so b-frag reads are 16B contiguous, 2-way aliasing (free).
__global__ __launch_bounds__(256) void mm0_kernel(
    const float* __restrict__ nf, const int* __restrict__ input_nodes,
    const _Float16* __restrict__ hn0,
    const float* __restrict__ Wself, const float* __restrict__ Wneigh,
    const float* __restrict__ bias, _Float16* __restrict__ h1) {
    __shared__ _Float16 Wt[128][256];   // 64 KB
    const int tid = threadIdx.x;
    for (int i = tid; i < 128 * 256; i += 256) {
        int k = i >> 7, n = i & 127;
        float w = (k < 128) ? Wself[k * 128 + n] : Wneigh[(k - 128) * 128 + n];
        Wt[n][((((k >> 3) ^ n) & 31) << 3) | (k & 7)] = (_Float16)w;
    }
    __syncthreads();

    const int waveId = tid >> 6, lane = tid & 63;
    const int quad = lane >> 4;
    const int m = lane & 15;
    const int row = blockIdx.x * 64 + waveId * 16 + m;
    const int g = input_nodes[row];
    const float* __restrict__ srow = nf + (long)g * D;
    const _Float16* __restrict__ nrow = hn0 + (long)row * D;

    f32x4 acc[8];
#pragma unroll
    for (int c = 0; c < 8; c++) { acc[c][0] = 0.f; acc[c][1] = 0.f; acc[c][2] = 0.f; acc[c][3] = 0.f; }

#pragma unroll
    for (int s = 0; s < 8; s++) {
        half8 a;
        if (s < 4) {
            const int k0 = s * 32 + quad * 8;
            float4 u = *(const float4*)(srow + k0);
            float4 v = *(const float4*)(srow + k0 + 4);
            a[0] = (_Float16)u.x; a[1] = (_Float16)u.y; a[2] = (_Float16)u.z; a[3] = (_Float16)u.w;
            a[4] = (_Float16)v.x; a[5] = (_Float16)v.y; a[6] = (_Float16)v.z; a[7] = (_Float16)v.w;
        } else {
            const int k0 = (s - 4) * 32 + quad * 8;
            a = *(const half8*)(nrow + k0);
        }
        const int kb = s * 4 + quad;
#pragma unroll
        for (int c = 0; c < 8; c++) {
            const int n = c * 16 + m;
            half8 b = *(const half8*)&Wt[n][((kb ^ (n & 31)) & 31) << 3];
            acc[c] = __builtin_amdgcn_mfma_f32_16x16x32_f16(a, b, acc[c], 0, 0, 0);
        }
    }

    const int orow = blockIdx.x * 64 + waveId * 16 + quad * 4;
#pragma unroll
    for (int c = 0; c < 8; c++) {
        const int col = c * 16 + m;
        const float bb = bias[col];
#pragma unroll
        for (int r = 0; r < 4; r++) {
            float vv = acc[c][r] + bb;
            vv = fmaxf(vv, 0.0f);
            h1[(long)(orow + r) * D + col] = (_Float16)vv;
        }
    }
}

// ---------------------------------------------------------------------------
// mm1: h2 = [h1_self | neigh_mean] @ [Wself1; Wneigh1] + b1, fp32 out, no relu
__global__ __launch_bounds__(256) void mm1_kernel(
    const _Float16* __restrict__ h1, const _Float16* __restrict__ hn1,
    const float* __restrict__ Wself, const float* __restrict__ Wneigh,
    const float* __restrict__ bias, float* __restrict__ h2) {
    __shared__ _Float16 Wt[128][256];
    const int tid = threadIdx.x;
    for (int i = tid; i < 128 * 256; i += 256) {
        int k = i >> 7, n = i & 127;
        float w = (k < 128) ? Wself[k * 128 + n] : Wneigh[(k - 128) * 128 + n];
        Wt[n][((((k >> 3) ^ n) & 31) << 3) | (k & 7)] = (_Float16)w;
    }
    __syncthreads();

    const int waveId = tid >> 6, lane = tid & 63;
    const int quad = lane >> 4;
    const int m = lane & 15;
    const int row = blockIdx.x * 64 + waveId * 16 + m;
    const _Float16* __restrict__ srow = h1 + (long)row * D;
    const _Float16* __restrict__ nrow = hn1 + (long)row * D;

    f32x4 acc[8];
#pragma unroll
    for (int c = 0; c < 8; c++) { acc[c][0] = 0.f; acc[c][1] = 0.f; acc[c][2] = 0.f; acc[c][3] = 0.f; }

#pragma unroll
    for (int s = 0; s < 8; s++) {
        half8 a;
        if (s < 4) {
            a = *(const half8*)(srow + s * 32 + quad * 8);
        } else {
            a = *(const half8*)(nrow + (s - 4) * 32 + quad * 8);
        }
        const int kb = s * 4 + quad;
#pragma unroll
        for (int c = 0; c < 8; c++) {
            const int n = c * 16 + m;
            half8 b = *(const half8*)&Wt[n][((kb ^ (n & 31)) & 31) << 3];
            acc[c] = __builtin_amdgcn_mfma_f32_16x16x32_f16(a, b, acc[c], 0, 0, 0);
        }
    }

    const int orow = blockIdx.x * 64 + waveId * 16 + quad * 4;
#pragma unroll
    for (int c = 0; c < 8; c++) {
        const int col = c * 16 + m;
        const float bb = bias[col];
#pragma unroll
        for (int r = 0; r < 4; r++) {
            h2[(long)(orow + r) * D + col] = acc[c][r] + bb;
        }
    }
}

// ---------------------------------------------------------------------------
// final gather: out rows 0..16383 = h2[pos_src|pos_dst|neg_src|neg_dst]
__global__ __launch_bounds__(256) void gather_out_kernel(
    const float* __restrict__ h2,
    const int* __restrict__ i0, const int* __restrict__ i1,
    const int* __restrict__ i2, const int* __restrict__ i3,
    float* __restrict__ out) {
    int wave = (blockIdx.x * 256 + threadIdx.x) >> 6;
    int lane = threadIdx.x & 63;
    int sel = wave >> 12;
    int i = wave & (P - 1);
    const int* arr = (sel == 0) ? i0 : (sel == 1) ? i1 : (sel == 2) ? i2 : i3;
    int idx = arr[i];
    float2 v = *(const float2*)(h2 + (long)idx * D + lane * 2);
    *(float2*)(out + (long)wave * D + lane * 2) = v;
}

// ---------------------------------------------------------------------------
extern "C" void kernel_launch(void* const* d_in, const int* in_sizes, int n_in,
                              void* d_out, int out_size, void* d_ws, size_t ws_size,
                              hipStream_t stream) {
    const float* nf          = (const float*)d_in[0];
    const int* input_nodes   = (const int*)d_in[1];
    const int* esrc0         = (const int*)d_in[2];
    const int* edst0         = (const int*)d_in[3];
    const int* esrc1         = (const int*)d_in[4];
    const int* edst1         = (const int*)d_in[5];
    const int* pos_src       = (const int*)d_in[6];
    const int* pos_dst       = (const int*)d_in[7];
    const int* neg_src       = (const int*)d_in[8];
    const int* neg_dst       = (const int*)d_in[9];
    const float* Wself0      = (const float*)d_in[10];
    const float* Wneigh0     = (const float*)d_in[11];
    const float* b0          = (const float*)d_in[12];
    const float* Wself1      = (const float*)d_in[13];
    const float* Wneigh1     = (const float*)d_in[14];
    const float* b1          = (const float*)d_in[15];

    char* ws = (char*)d_ws;
    int* cnt  = (int*)ws; ws += (size_t)NCNT * 4;
    int* off  = (int*)ws; ws += (size_t)NCNT * 4;
    int* bsum = (int*)ws; ws += 64 * 4;
    int* eg   = (int*)ws; ws += (size_t)(E0 + E1) * 4;
    _Float16* hn0 = (_Float16*)ws; ws += (size_t)N1 * D * 2;
    _Float16* h1  = (_Float16*)ws; ws += (size_t)N1 * D * 2;
    _Float16* hn1 = (_Float16*)ws; ws += (size_t)N2 * D * 2;
    float* h2     = (float*)ws; ws += (size_t)N2 * D * 4;

    const int EALL = E0 + E1;

    zero_kernel<<<(NCNT + 255) / 256, 256, 0, stream>>>(cnt, NCNT);
    hist_kernel<<<(EALL + 255) / 256, 256, 0, stream>>>(edst0, edst1, cnt);
    scanA_kernel<<<NB, 1024, 0, stream>>>(cnt, off, bsum);
    scanB_kernel<<<1, 64, 0, stream>>>(bsum);
    scanC_kernel<<<NB, 1024, 0, stream>>>(off, bsum);
    scatter_kernel<<<(EALL + 255) / 256, 256, 0, stream>>>(
        esrc0, edst0, esrc1, edst1, input_nodes, off, eg);

    agg0_kernel<<<(N1 * 64 + 255) / 256, 256, 0, stream>>>(nf, cnt, off, eg, hn0);
    mm0_kernel<<<N1 / 64, 256, 0, stream>>>(nf, input_nodes, hn0, Wself0, Wneigh0, b0, h1);
    agg1_kernel<<<(N2 * 64 + 255) / 256, 256, 0, stream>>>(h1, cnt, off, eg, hn1);
    mm1_kernel<<<N2 / 64, 256, 0, stream>>>(h1, hn1, Wself1, Wneigh1, b1, h2);
    gather_out_kernel<<<(4 * P) / 4, 256, 0, stream>>>(h2, pos_src, pos_dst,
                                                       neg_src, neg_dst, (float*)d_out);
}